// Round 6
// baseline (460.775 us; speedup 1.0000x reference)
//
#include <hip/hip_runtime.h>
#include <hip/hip_bf16.h>
#include <cstdint>
#include <cstddef>

#define NN 100000
#define NNP 100096            // padded to 782*128
#define NE 1600000
#define HID 128
#define BKN 128               // nodes per bucket
#define NBUK 782              // ceil(NN/128)
#define NBB 391               // ceil(NE/4096) edge blocks
#define ECH 4096              // edges per block in bin passes
#define CAP 2816              // LDS edge-list capacity (mean 2048, +17 sigma)

typedef unsigned int u32;
typedef unsigned short u16;
typedef __bf16 bf16x8 __attribute__((ext_vector_type(8)));
typedef float f32x16 __attribute__((ext_vector_type(16)));

__device__ inline u32 pack2(float a, float b) {
    u16 x = __builtin_bit_cast(u16, (__bf16)a);
    u16 y = __builtin_bit_cast(u16, (__bf16)b);
    return (u32)x | ((u32)y << 16);
}
__device__ inline float b2f(u16 v) { return __uint_as_float((u32)v << 16); }

// ---------------- CSR build: bucket counting sort (128-node buckets) ----------------

__global__ __launch_bounds__(256) void bincount_kernel(const int* __restrict__ dst,
                                                       u32* __restrict__ bcnt) {
    __shared__ u32 lh[NBUK];
    int tid = threadIdx.x;
    for (int i = tid; i < NBUK; i += 256) lh[i] = 0;
    __syncthreads();
    int e0 = blockIdx.x * ECH;
    for (int i = tid; i < ECH; i += 256) {
        int e = e0 + i;
        if (e < NE) atomicAdd(&lh[(u32)dst[e] >> 7], 1u);
    }
    __syncthreads();
    for (int i = tid; i < NBUK; i += 256)
        if (lh[i]) atomicAdd(&bcnt[i], lh[i]);
}

// exclusive scan of 782 bucket counts (single block, 4 chunks with carry)
__global__ __launch_bounds__(256) void bucketscan_kernel(const u32* __restrict__ bcnt,
                                                         u32* __restrict__ boff,
                                                         u32* __restrict__ bcur) {
    __shared__ u32 s[256];
    __shared__ u32 carry;
    int t = threadIdx.x;
    if (t == 0) carry = 0;
    __syncthreads();
#pragma unroll 1
    for (int c = 0; c < 4; ++c) {
        int idx = c * 256 + t;
        u32 v = (idx < NBUK) ? bcnt[idx] : 0u;
        s[t] = v;
        __syncthreads();
        for (int off = 1; off < 256; off <<= 1) {
            u32 a = (t >= off) ? s[t - off] : 0u;
            __syncthreads();
            s[t] += a;
            __syncthreads();
        }
        u32 run = carry;
        u32 excl = run + s[t] - v;
        if (idx <= NBUK) boff[idx] = excl;
        if (idx < NBUK) bcur[idx] = excl;
        __syncthreads();
        if (t == 255) carry = run + s[255];
        __syncthreads();
    }
}

// partition edges into bucket regions; payload = dlow(7) | src(17) | attr(3)
__global__ __launch_bounds__(256) void binscatter_kernel(const int* __restrict__ src,
                                                         const int* __restrict__ dst,
                                                         const int* __restrict__ attr,
                                                         u32* __restrict__ bcur,
                                                         u32* __restrict__ binned) {
    __shared__ u32 lh[NBUK], rb[NBUK], rc[NBUK];
    int tid = threadIdx.x;
    for (int i = tid; i < NBUK; i += 256) { lh[i] = 0; rc[i] = 0; }
    __syncthreads();
    int e0 = blockIdx.x * ECH;
    for (int i = tid; i < ECH; i += 256) {
        int e = e0 + i;
        if (e < NE) atomicAdd(&lh[(u32)dst[e] >> 7], 1u);
    }
    __syncthreads();
    for (int i = tid; i < NBUK; i += 256)
        if (lh[i]) rb[i] = atomicAdd(&bcur[i], lh[i]);
    __syncthreads();
    for (int i = tid; i < ECH; i += 256) {
        int e = e0 + i;
        if (e < NE) {
            u32 d = (u32)dst[e];
            u32 b = d >> 7;
            u32 pos = rb[b] + atomicAdd(&rc[b], 1u);
            binned[pos] = (d & 127u) | ((u32)src[e] << 7) | ((u32)attr[e] << 24);
        }
    }
}

// ---------------- fused bucket-CSR + aggregation ----------------
// One block per 128-node bucket: local hist+scan+scatter into LDS edge list,
// then per-node register-accumulated gather-aggregate. agg = bf16.

__global__ __launch_bounds__(256) void bucket_agg_kernel(const u32* __restrict__ boff,
                                                         const u32* __restrict__ binned,
                                                         const u16* __restrict__ h,
                                                         const float* __restrict__ emb,
                                                         u16* __restrict__ agg) {
    __shared__ u32 epl[CAP];
    __shared__ u32 hist[BKN + 1];
    __shared__ u32 hcur[BKN];
    __shared__ u32 s[256];
    __shared__ float semb[8 * HID];
    int tid = threadIdx.x;
    int buk = blockIdx.x;
    u32 base = boff[buk];
    u32 cnt = boff[buk + 1] - base;

    if (tid < BKN) hist[tid] = 0;
    ((float4*)semb)[tid] = ((const float4*)emb)[tid];
    __syncthreads();

    // (a) node histogram within bucket
    for (u32 i = tid; i < cnt; i += 256)
        atomicAdd(&hist[binned[base + i] & 127u], 1u);
    __syncthreads();

    // (b) 128-wide exclusive scan
    u32 v = (tid < BKN) ? hist[tid] : 0u;
    s[tid] = v;
    __syncthreads();
    for (int off = 1; off < 256; off <<= 1) {
        u32 a = (tid >= off) ? s[tid - off] : 0u;
        __syncthreads();
        s[tid] += a;
        __syncthreads();
    }
    if (tid < BKN) {
        u32 excl = s[tid] - v;
        hist[tid] = excl;
        hcur[tid] = excl;
    }
    if (tid == 0) hist[BKN] = cnt;
    __syncthreads();

    // (c) scatter into LDS edge list (payload: src | attr<<17)
    for (u32 i = tid; i < cnt; i += 256) {
        u32 w = binned[base + i];
        u32 pos = atomicAdd(&hcur[w & 127u], 1u);
        epl[pos] = w >> 7;
    }
    __syncthreads();

    // (d) per-node aggregate: wave per node, 8-deep gather batching
    int wv = tid >> 6, l = tid & 63;
    const u32* h32 = (const u32*)h;
    const float2* e2 = (const float2*)semb;
    int n0 = buk * BKN;
    for (int n = wv; n < BKN; n += 4) {
        int gnode = n0 + n;
        if (gnode >= NN) break;
        u32 j = hist[n], j1 = hist[n + 1];
        float ax = 0.f, ay = 0.f;
        for (; j + 8 <= j1; j += 8) {
            u32 e[8];
#pragma unroll
            for (int t = 0; t < 8; ++t) e[t] = epl[j + t];
            u32 hv[8];
#pragma unroll
            for (int t = 0; t < 8; ++t) hv[t] = h32[(size_t)(e[t] & 0x1FFFFu) * 64 + l];
            float2 ev[8];
#pragma unroll
            for (int t = 0; t < 8; ++t) ev[t] = e2[(e[t] >> 17) * 64 + l];
#pragma unroll
            for (int t = 0; t < 8; ++t) {
                ax += fmaxf(__uint_as_float(hv[t] << 16) + ev[t].x, 0.f);
                ay += fmaxf(__uint_as_float(hv[t] & 0xFFFF0000u) + ev[t].y, 0.f);
            }
        }
        if (j + 4 <= j1) {
            u32 e[4];
#pragma unroll
            for (int t = 0; t < 4; ++t) e[t] = epl[j + t];
            u32 hv[4];
#pragma unroll
            for (int t = 0; t < 4; ++t) hv[t] = h32[(size_t)(e[t] & 0x1FFFFu) * 64 + l];
            float2 ev[4];
#pragma unroll
            for (int t = 0; t < 4; ++t) ev[t] = e2[(e[t] >> 17) * 64 + l];
#pragma unroll
            for (int t = 0; t < 4; ++t) {
                ax += fmaxf(__uint_as_float(hv[t] << 16) + ev[t].x, 0.f);
                ay += fmaxf(__uint_as_float(hv[t] & 0xFFFF0000u) + ev[t].y, 0.f);
            }
            j += 4;
        }
        for (; j < j1; j++) {
            u32 e = epl[j];
            u32 hv = h32[(size_t)(e & 0x1FFFFu) * 64 + l];
            float2 ev = e2[(e >> 17) * 64 + l];
            ax += fmaxf(__uint_as_float(hv << 16) + ev.x, 0.f);
            ay += fmaxf(__uint_as_float(hv & 0xFFFF0000u) + ev.y, 0.f);
        }
        ((u32*)agg)[(size_t)gnode * 64 + l] = pack2(ax, ay);
    }
}

// ---------------- W pre-transpose: W[k][n] fp32 -> Wt[n][k] bf16 ----------------

__global__ __launch_bounds__(256) void wt_kernel(const float* __restrict__ W0,
                                                 const float* __restrict__ W1,
                                                 const float* __restrict__ W2,
                                                 const float* __restrict__ W3,
                                                 const float* __restrict__ W4,
                                                 const float* __restrict__ W5,
                                                 const float* __restrict__ W6,
                                                 u32* __restrict__ Wt) {
    __shared__ float s[64][129];
    int m = blockIdx.x >> 1, h = blockIdx.x & 1;
    const float* W = (m == 0) ? W0 : (m == 1) ? W1 : (m == 2) ? W2 : (m == 3) ? W3
                   : (m == 4) ? W4 : (m == 5) ? W5 : W6;
    int tid = threadIdx.x;
#pragma unroll
    for (int it = 0; it < 8; ++it) {
        int u = it * 256 + tid;
        int r = u >> 5, c4 = (u & 31) * 4;
        float4 v = *(const float4*)&W[(size_t)(64 * h + r) * HID + c4];
        s[r][c4] = v.x; s[r][c4 + 1] = v.y; s[r][c4 + 2] = v.z; s[r][c4 + 3] = v.w;
    }
    __syncthreads();
    u32* outm = Wt + (size_t)m * 8192;
#pragma unroll
    for (int it = 0; it < 16; ++it) {
        int u = it * 256 + tid;
        int n = u >> 5, kpl = u & 31;
        u32 v = pack2(s[2 * kpl][n], s[2 * kpl + 1][n]);
        outm[(size_t)n * 64 + 32 * h + kpl] = v;
    }
}

// ---------------- MFMA MLP (unchanged, verified since R3) ----------------

__device__ inline void stageWt(char* sW, const uint4* __restrict__ Wt4, int tid) {
#pragma unroll
    for (int it = 0; it < 8; ++it) {
        int u = it * 256 + tid;
        int n = u >> 4, c = u & 15;
        uint4 v = Wt4[(size_t)n * 16 + c];
        *(uint4*)(sW + n * 256 + ((c * 16) ^ ((n & 15) << 4))) = v;
    }
}

template <int NL, int MODE, bool OUTB>
__global__ __launch_bounds__(256, 2) void mlp_mfma(
    const void* __restrict__ inp, const u16* __restrict__ aggb,
    const float* __restrict__ epsp, void* __restrict__ outp,
    const u32* __restrict__ Wt0, const float* __restrict__ b0,
    const u32* __restrict__ Wt1, const float* __restrict__ b1,
    const u32* __restrict__ Wt2, const float* __restrict__ b2) {
    __shared__ __align__(16) char sA[128 * 256];
    __shared__ __align__(16) char sW[128 * 256];
    int tid = threadIdx.x;
    int row0 = blockIdx.x * 128;

    if (MODE == 0) {
        const float* x = (const float*)inp;
#pragma unroll
        for (int it = 0; it < 16; ++it) {
            int idx = it * 256 + tid;
            int r = idx >> 5, c4 = (idx & 31) * 4;
            int grow = row0 + r;
            uint2 pk = make_uint2(0u, 0u);
            if (grow < NN) {
                float4 v = *(const float4*)&x[(size_t)grow * HID + c4];
                pk.x = pack2(v.x, v.y);
                pk.y = pack2(v.z, v.w);
            }
            *(uint2*)(sA + r * 256 + ((c4 * 2) ^ ((r & 15) << 4))) = pk;
        }
    } else {
        const u16* hin = (const u16*)inp;
        float eps = 1.0f + epsp[0];
#pragma unroll
        for (int it = 0; it < 16; ++it) {
            int idx = it * 256 + tid;
            int r = idx >> 5, c4 = (idx & 31) * 4;
            int grow = row0 + r;
            uint2 pk = make_uint2(0u, 0u);
            if (grow < NN) {
                ushort4 hv = *(const ushort4*)&hin[(size_t)grow * HID + c4];
                ushort4 gv = *(const ushort4*)&aggb[(size_t)grow * HID + c4];
                pk.x = pack2(eps * b2f(hv.x) + b2f(gv.x), eps * b2f(hv.y) + b2f(gv.y));
                pk.y = pack2(eps * b2f(hv.z) + b2f(gv.z), eps * b2f(hv.w) + b2f(gv.w));
            }
            *(uint2*)(sA + r * 256 + ((c4 * 2) ^ ((r & 15) << 4))) = pk;
        }
    }
    stageWt(sW, (const uint4*)Wt0, tid);
    __syncthreads();

    int lane = tid & 63, w = tid >> 6;
    int lo5 = lane & 31, hi = lane >> 5;
    int swzkey = (lo5 & 15) << 4;

#pragma unroll 1
    for (int l = 0; l < NL; ++l) {
        const float* bl = (l == 0) ? b0 : ((l == 1) ? b1 : b2);
        f32x16 acc[4];
#pragma unroll
        for (int nf = 0; nf < 4; ++nf) {
            float bv = bl[nf * 32 + lo5];
#pragma unroll
            for (int i = 0; i < 16; ++i) acc[nf][i] = bv;
        }
#pragma unroll
        for (int kc = 0; kc < 8; ++kc) {
            int koff = kc * 32 + hi * 16;
            bf16x8 a = *(const bf16x8*)(sA + (32 * w + lo5) * 256 + (koff ^ swzkey));
#pragma unroll
            for (int nf = 0; nf < 4; ++nf) {
                bf16x8 bb = *(const bf16x8*)(sW + (nf * 32 + lo5) * 256 + (koff ^ swzkey));
                acc[nf] = __builtin_amdgcn_mfma_f32_32x32x16_bf16(a, bb, acc[nf], 0, 0, 0);
            }
        }
        if (l + 1 < NL) {
            __syncthreads();
            stageWt(sW, (const uint4*)((l == 0) ? Wt1 : Wt2), tid);
#pragma unroll
            for (int nf = 0; nf < 4; ++nf) {
#pragma unroll
                for (int reg = 0; reg < 16; ++reg) {
                    int r32 = (reg & 3) + 8 * (reg >> 2) + 4 * hi;
                    int col = nf * 32 + lo5;
                    float v = fmaxf(acc[nf][reg], 0.f);
                    *(u16*)(sA + (32 * w + r32) * 256 + ((col * 2) ^ ((r32 & 15) << 4))) =
                        __builtin_bit_cast(u16, (__bf16)v);
                }
            }
            __syncthreads();
        } else {
#pragma unroll
            for (int nf = 0; nf < 4; ++nf) {
#pragma unroll
                for (int reg = 0; reg < 16; ++reg) {
                    int r32 = (reg & 3) + 8 * (reg >> 2) + 4 * hi;
                    int grow = row0 + 32 * w + r32;
                    int col = nf * 32 + lo5;
                    float v = fmaxf(acc[nf][reg], 0.f);
                    if (grow < NN) {
                        if (OUTB)
                            ((u16*)outp)[(size_t)grow * HID + col] =
                                __builtin_bit_cast(u16, (__bf16)v);
                        else
                            ((float*)outp)[(size_t)grow * HID + col] = v;
                    }
                }
            }
        }
    }
}

// ---------------- launch ----------------

extern "C" void kernel_launch(void* const* d_in, const int* in_sizes, int n_in,
                              void* d_out, int out_size, void* d_ws, size_t ws_size,
                              hipStream_t stream) {
    const float* x    = (const float*)d_in[0];
    const int*   ei   = (const int*)d_in[1];
    const int*   ea   = (const int*)d_in[2];
    const float* Wx   = (const float*)d_in[3];
    const float* bx   = (const float*)d_in[4];
    const float* emb  = (const float*)d_in[5];
    const float* eps1 = (const float*)d_in[6];
    const float* eps2 = (const float*)d_in[7];
    const float* W1a = (const float*)d_in[8],  *b1a = (const float*)d_in[9];
    const float* W1b = (const float*)d_in[10], *b1b = (const float*)d_in[11];
    const float* W1c = (const float*)d_in[12], *b1c = (const float*)d_in[13];
    const float* W2a = (const float*)d_in[14], *b2a = (const float*)d_in[15];
    const float* W2b = (const float*)d_in[16], *b2b = (const float*)d_in[17];
    const float* W2c = (const float*)d_in[18], *b2c = (const float*)d_in[19];
    float* out = (float*)d_out;

    const int* srcp = ei;
    const int* dstp = ei + NE;

    char* ws = (char*)d_ws;
    u16* h16   = (u16*)ws;                                          // 25.6MB
    size_t off = (size_t)NNP * HID * 2;
    u16* agg16 = (u16*)(ws + off); off += (size_t)NNP * HID * 2;    // 25.6MB
    u32* bcnt = (u32*)(ws + off); off += 800 * 4;
    u32* boff = (u32*)(ws + off); off += 800 * 4;
    u32* bcur = (u32*)(ws + off); off += 800 * 4;
    u32* binned = (u32*)(ws + off); off += (size_t)NE * 4;          // 6.4MB
    u32* Wt   = (u32*)(ws + off); off += 7 * 8192 * 4;

    hipMemsetAsync(bcnt, 0, 800 * 4, stream);

    // pre-transpose all 7 weight matrices to bf16 Wt[n][k]
    wt_kernel<<<14, 256, 0, stream>>>(Wx, W1a, W1b, W1c, W2a, W2b, W2c, Wt);

    // h = relu(x @ Wx + bx)  -> bf16
    mlp_mfma<1, 0, true><<<NNP / 128, 256, 0, stream>>>(
        x, nullptr, nullptr, h16, Wt, bx, nullptr, nullptr, nullptr, nullptr);

    // bucket sort of edges (128-node buckets)
    bincount_kernel<<<NBB, 256, 0, stream>>>(dstp, bcnt);
    bucketscan_kernel<<<1, 256, 0, stream>>>(bcnt, boff, bcur);
    binscatter_kernel<<<NBB, 256, 0, stream>>>(srcp, dstp, ea, bcur, binned);

    // layer 1: fused bucket-CSR + aggregation, then MLP (in-place on h16)
    bucket_agg_kernel<<<NBUK, 256, 0, stream>>>(boff, binned, h16, emb, agg16);
    mlp_mfma<3, 1, true><<<NNP / 128, 256, 0, stream>>>(
        h16, agg16, eps1, h16, Wt + 8192, b1a, Wt + 2 * 8192, b1b, Wt + 3 * 8192, b1c);

    // layer 2 -> d_out fp32
    bucket_agg_kernel<<<NBUK, 256, 0, stream>>>(boff, binned, h16, emb, agg16);
    mlp_mfma<3, 1, false><<<NNP / 128, 256, 0, stream>>>(
        h16, agg16, eps2, out, Wt + 4 * 8192, b2a, Wt + 5 * 8192, b2b, Wt + 6 * 8192, b2c);
}

// Round 7
// 417.905 us; speedup vs baseline: 1.1026x; 1.1026x over previous
//
#include <hip/hip_runtime.h>
#include <hip/hip_bf16.h>
#include <cstdint>
#include <cstddef>

#define NN 100000
#define NNP 100096            // padded to 782*128
#define NE 1600000
#define HID 128
#define BKN 128               // nodes per bucket
#define NBUK 782              // ceil(NN/128)
#define NBB 391               // ceil(NE/4096) edge blocks
#define ECH 4096              // edges per block in bin pass
#define CAP 2368              // fixed region per bucket (mean 2046, exp-max ~2211)

typedef unsigned int u32;
typedef unsigned short u16;
typedef __bf16 bf16x8 __attribute__((ext_vector_type(8)));
typedef float f32x16 __attribute__((ext_vector_type(16)));

__device__ inline u32 pack2(float a, float b) {
    u16 x = __builtin_bit_cast(u16, (__bf16)a);
    u16 y = __builtin_bit_cast(u16, (__bf16)b);
    return (u32)x | ((u32)y << 16);
}
__device__ inline float b2f(u16 v) { return __uint_as_float((u32)v << 16); }

// ---------------- edge partition into fixed bucket regions ----------------
// payload = dlow(7) | src(17)<<7 | attr(3)<<24

__global__ __launch_bounds__(256) void binscatter_kernel(const int* __restrict__ src,
                                                         const int* __restrict__ dst,
                                                         const int* __restrict__ attr,
                                                         u32* __restrict__ bcnt,
                                                         u32* __restrict__ binned) {
    __shared__ u32 lh[NBUK], rb[NBUK], rc[NBUK];
    int tid = threadIdx.x;
    for (int i = tid; i < NBUK; i += 256) { lh[i] = 0; rc[i] = 0; }
    __syncthreads();
    int e0 = blockIdx.x * ECH;
    for (int i = tid; i < ECH; i += 256) {
        int e = e0 + i;
        if (e < NE) atomicAdd(&lh[(u32)dst[e] >> 7], 1u);
    }
    __syncthreads();
    for (int i = tid; i < NBUK; i += 256)
        if (lh[i]) rb[i] = atomicAdd(&bcnt[i], lh[i]);
    __syncthreads();
    for (int i = tid; i < ECH; i += 256) {
        int e = e0 + i;
        if (e < NE) {
            u32 d = (u32)dst[e];
            u32 b = d >> 7;
            u32 pos = rb[b] + atomicAdd(&rc[b], 1u);
            binned[(size_t)b * CAP + pos] = (d & 127u) | ((u32)src[e] << 7) | ((u32)attr[e] << 24);
        }
    }
}

// ---------------- fused bucket-CSR + aggregation (512 threads / 8 waves) ----------------

__global__ __launch_bounds__(512) void bucket_agg_kernel(const u32* __restrict__ bcnt,
                                                         const u32* __restrict__ binned,
                                                         const u16* __restrict__ h,
                                                         const float* __restrict__ emb,
                                                         u16* __restrict__ agg) {
    __shared__ u32 epl[CAP];
    __shared__ u32 hist[BKN + 1];
    __shared__ u32 hcur[BKN];
    __shared__ u32 s[BKN];
    __shared__ float semb[8 * HID];
    int tid = threadIdx.x;
    int buk = blockIdx.x;
    size_t base = (size_t)buk * CAP;
    u32 cnt = bcnt[buk];

    if (tid < BKN) hist[tid] = 0;
    if (tid < 256) ((float4*)semb)[tid] = ((const float4*)emb)[tid];
    __syncthreads();

    // (a) node histogram within bucket
    for (u32 i = tid; i < cnt; i += 512)
        atomicAdd(&hist[binned[base + i] & 127u], 1u);
    __syncthreads();

    // (b) 128-wide exclusive scan (Hillis-Steele on first 128 threads)
    u32 v = 0;
    if (tid < BKN) { v = hist[tid]; s[tid] = v; }
    __syncthreads();
#pragma unroll
    for (int off = 1; off < BKN; off <<= 1) {
        u32 a = (tid < BKN && tid >= off) ? s[tid - off] : 0u;
        __syncthreads();
        if (tid < BKN) s[tid] += a;
        __syncthreads();
    }
    if (tid < BKN) {
        u32 excl = s[tid] - v;
        hist[tid] = excl;
        hcur[tid] = excl;
    }
    if (tid == 0) hist[BKN] = cnt;
    __syncthreads();

    // (c) scatter into LDS edge list (payload: src | attr<<17)
    for (u32 i = tid; i < cnt; i += 512) {
        u32 w = binned[base + i];
        u32 pos = atomicAdd(&hcur[w & 127u], 1u);
        epl[pos] = w >> 7;
    }
    __syncthreads();

    // (d) per-node aggregate: wave per node, 8-deep gather batching
    int wv = tid >> 6, l = tid & 63;
    const u32* h32 = (const u32*)h;
    const float2* e2 = (const float2*)semb;
    int n0 = buk * BKN;
    for (int n = wv; n < BKN; n += 8) {
        int gnode = n0 + n;
        if (gnode >= NN) break;
        u32 j = hist[n], j1 = hist[n + 1];
        float ax = 0.f, ay = 0.f;
        for (; j + 8 <= j1; j += 8) {
            u32 e[8];
#pragma unroll
            for (int t = 0; t < 8; ++t) e[t] = epl[j + t];
            u32 hv[8];
#pragma unroll
            for (int t = 0; t < 8; ++t) hv[t] = h32[(size_t)(e[t] & 0x1FFFFu) * 64 + l];
            float2 ev[8];
#pragma unroll
            for (int t = 0; t < 8; ++t) ev[t] = e2[(e[t] >> 17) * 64 + l];
#pragma unroll
            for (int t = 0; t < 8; ++t) {
                ax += fmaxf(__uint_as_float(hv[t] << 16) + ev[t].x, 0.f);
                ay += fmaxf(__uint_as_float(hv[t] & 0xFFFF0000u) + ev[t].y, 0.f);
            }
        }
        if (j + 4 <= j1) {
            u32 e[4];
#pragma unroll
            for (int t = 0; t < 4; ++t) e[t] = epl[j + t];
            u32 hv[4];
#pragma unroll
            for (int t = 0; t < 4; ++t) hv[t] = h32[(size_t)(e[t] & 0x1FFFFu) * 64 + l];
            float2 ev[4];
#pragma unroll
            for (int t = 0; t < 4; ++t) ev[t] = e2[(e[t] >> 17) * 64 + l];
#pragma unroll
            for (int t = 0; t < 4; ++t) {
                ax += fmaxf(__uint_as_float(hv[t] << 16) + ev[t].x, 0.f);
                ay += fmaxf(__uint_as_float(hv[t] & 0xFFFF0000u) + ev[t].y, 0.f);
            }
            j += 4;
        }
        for (; j < j1; j++) {
            u32 e = epl[j];
            u32 hv = h32[(size_t)(e & 0x1FFFFu) * 64 + l];
            float2 ev = e2[(e >> 17) * 64 + l];
            ax += fmaxf(__uint_as_float(hv << 16) + ev.x, 0.f);
            ay += fmaxf(__uint_as_float(hv & 0xFFFF0000u) + ev.y, 0.f);
        }
        ((u32*)agg)[(size_t)gnode * 64 + l] = pack2(ax, ay);
    }
}

// ---------------- W pre-transpose (also zeroes bcnt) ----------------

__global__ __launch_bounds__(256) void wt_kernel(const float* __restrict__ W0,
                                                 const float* __restrict__ W1,
                                                 const float* __restrict__ W2,
                                                 const float* __restrict__ W3,
                                                 const float* __restrict__ W4,
                                                 const float* __restrict__ W5,
                                                 const float* __restrict__ W6,
                                                 u32* __restrict__ Wt,
                                                 u32* __restrict__ bcnt) {
    __shared__ float s[64][129];
    int m = blockIdx.x >> 1, h = blockIdx.x & 1;
    const float* W = (m == 0) ? W0 : (m == 1) ? W1 : (m == 2) ? W2 : (m == 3) ? W3
                   : (m == 4) ? W4 : (m == 5) ? W5 : W6;
    int tid = threadIdx.x;
    if (blockIdx.x == 0)
        for (int i = tid; i < NBUK; i += 256) bcnt[i] = 0;
#pragma unroll
    for (int it = 0; it < 8; ++it) {
        int u = it * 256 + tid;
        int r = u >> 5, c4 = (u & 31) * 4;
        float4 v = *(const float4*)&W[(size_t)(64 * h + r) * HID + c4];
        s[r][c4] = v.x; s[r][c4 + 1] = v.y; s[r][c4 + 2] = v.z; s[r][c4 + 3] = v.w;
    }
    __syncthreads();
    u32* outm = Wt + (size_t)m * 8192;
#pragma unroll
    for (int it = 0; it < 16; ++it) {
        int u = it * 256 + tid;
        int n = u >> 5, kpl = u & 31;
        u32 v = pack2(s[2 * kpl][n], s[2 * kpl + 1][n]);
        outm[(size_t)n * 64 + 32 * h + kpl] = v;
    }
}

// ---------------- MFMA MLP (unchanged, verified since R3) ----------------

__device__ inline void stageWt(char* sW, const uint4* __restrict__ Wt4, int tid) {
#pragma unroll
    for (int it = 0; it < 8; ++it) {
        int u = it * 256 + tid;
        int n = u >> 4, c = u & 15;
        uint4 v = Wt4[(size_t)n * 16 + c];
        *(uint4*)(sW + n * 256 + ((c * 16) ^ ((n & 15) << 4))) = v;
    }
}

template <int NL, int MODE, bool OUTB>
__global__ __launch_bounds__(256, 2) void mlp_mfma(
    const void* __restrict__ inp, const u16* __restrict__ aggb,
    const float* __restrict__ epsp, void* __restrict__ outp,
    const u32* __restrict__ Wt0, const float* __restrict__ b0,
    const u32* __restrict__ Wt1, const float* __restrict__ b1,
    const u32* __restrict__ Wt2, const float* __restrict__ b2) {
    __shared__ __align__(16) char sA[128 * 256];
    __shared__ __align__(16) char sW[128 * 256];
    int tid = threadIdx.x;
    int row0 = blockIdx.x * 128;

    if (MODE == 0) {
        const float* x = (const float*)inp;
#pragma unroll
        for (int it = 0; it < 16; ++it) {
            int idx = it * 256 + tid;
            int r = idx >> 5, c4 = (idx & 31) * 4;
            int grow = row0 + r;
            uint2 pk = make_uint2(0u, 0u);
            if (grow < NN) {
                float4 v = *(const float4*)&x[(size_t)grow * HID + c4];
                pk.x = pack2(v.x, v.y);
                pk.y = pack2(v.z, v.w);
            }
            *(uint2*)(sA + r * 256 + ((c4 * 2) ^ ((r & 15) << 4))) = pk;
        }
    } else {
        const u16* hin = (const u16*)inp;
        float eps = 1.0f + epsp[0];
#pragma unroll
        for (int it = 0; it < 16; ++it) {
            int idx = it * 256 + tid;
            int r = idx >> 5, c4 = (idx & 31) * 4;
            int grow = row0 + r;
            uint2 pk = make_uint2(0u, 0u);
            if (grow < NN) {
                ushort4 hv = *(const ushort4*)&hin[(size_t)grow * HID + c4];
                ushort4 gv = *(const ushort4*)&aggb[(size_t)grow * HID + c4];
                pk.x = pack2(eps * b2f(hv.x) + b2f(gv.x), eps * b2f(hv.y) + b2f(gv.y));
                pk.y = pack2(eps * b2f(hv.z) + b2f(gv.z), eps * b2f(hv.w) + b2f(gv.w));
            }
            *(uint2*)(sA + r * 256 + ((c4 * 2) ^ ((r & 15) << 4))) = pk;
        }
    }
    stageWt(sW, (const uint4*)Wt0, tid);
    __syncthreads();

    int lane = tid & 63, w = tid >> 6;
    int lo5 = lane & 31, hi = lane >> 5;
    int swzkey = (lo5 & 15) << 4;

#pragma unroll 1
    for (int l = 0; l < NL; ++l) {
        const float* bl = (l == 0) ? b0 : ((l == 1) ? b1 : b2);
        f32x16 acc[4];
#pragma unroll
        for (int nf = 0; nf < 4; ++nf) {
            float bv = bl[nf * 32 + lo5];
#pragma unroll
            for (int i = 0; i < 16; ++i) acc[nf][i] = bv;
        }
#pragma unroll
        for (int kc = 0; kc < 8; ++kc) {
            int koff = kc * 32 + hi * 16;
            bf16x8 a = *(const bf16x8*)(sA + (32 * w + lo5) * 256 + (koff ^ swzkey));
#pragma unroll
            for (int nf = 0; nf < 4; ++nf) {
                bf16x8 bb = *(const bf16x8*)(sW + (nf * 32 + lo5) * 256 + (koff ^ swzkey));
                acc[nf] = __builtin_amdgcn_mfma_f32_32x32x16_bf16(a, bb, acc[nf], 0, 0, 0);
            }
        }
        if (l + 1 < NL) {
            __syncthreads();
            stageWt(sW, (const uint4*)((l == 0) ? Wt1 : Wt2), tid);
#pragma unroll
            for (int nf = 0; nf < 4; ++nf) {
#pragma unroll
                for (int reg = 0; reg < 16; ++reg) {
                    int r32 = (reg & 3) + 8 * (reg >> 2) + 4 * hi;
                    int col = nf * 32 + lo5;
                    float v = fmaxf(acc[nf][reg], 0.f);
                    *(u16*)(sA + (32 * w + r32) * 256 + ((col * 2) ^ ((r32 & 15) << 4))) =
                        __builtin_bit_cast(u16, (__bf16)v);
                }
            }
            __syncthreads();
        } else {
#pragma unroll
            for (int nf = 0; nf < 4; ++nf) {
#pragma unroll
                for (int reg = 0; reg < 16; ++reg) {
                    int r32 = (reg & 3) + 8 * (reg >> 2) + 4 * hi;
                    int grow = row0 + 32 * w + r32;
                    int col = nf * 32 + lo5;
                    float v = fmaxf(acc[nf][reg], 0.f);
                    if (grow < NN) {
                        if (OUTB)
                            ((u16*)outp)[(size_t)grow * HID + col] =
                                __builtin_bit_cast(u16, (__bf16)v);
                        else
                            ((float*)outp)[(size_t)grow * HID + col] = v;
                    }
                }
            }
        }
    }
}

// ---------------- launch ----------------

extern "C" void kernel_launch(void* const* d_in, const int* in_sizes, int n_in,
                              void* d_out, int out_size, void* d_ws, size_t ws_size,
                              hipStream_t stream) {
    const float* x    = (const float*)d_in[0];
    const int*   ei   = (const int*)d_in[1];
    const int*   ea   = (const int*)d_in[2];
    const float* Wx   = (const float*)d_in[3];
    const float* bx   = (const float*)d_in[4];
    const float* emb  = (const float*)d_in[5];
    const float* eps1 = (const float*)d_in[6];
    const float* eps2 = (const float*)d_in[7];
    const float* W1a = (const float*)d_in[8],  *b1a = (const float*)d_in[9];
    const float* W1b = (const float*)d_in[10], *b1b = (const float*)d_in[11];
    const float* W1c = (const float*)d_in[12], *b1c = (const float*)d_in[13];
    const float* W2a = (const float*)d_in[14], *b2a = (const float*)d_in[15];
    const float* W2b = (const float*)d_in[16], *b2b = (const float*)d_in[17];
    const float* W2c = (const float*)d_in[18], *b2c = (const float*)d_in[19];
    float* out = (float*)d_out;

    const int* srcp = ei;
    const int* dstp = ei + NE;

    char* ws = (char*)d_ws;
    u16* h16   = (u16*)ws;                                          // 25.6MB
    size_t off = (size_t)NNP * HID * 2;
    u16* agg16 = (u16*)(ws + off); off += (size_t)NNP * HID * 2;    // 25.6MB
    u32* bcnt  = (u32*)(ws + off); off += 800 * 4;
    u32* binned = (u32*)(ws + off); off += (size_t)NBUK * CAP * 4;  // 7.4MB
    u32* Wt    = (u32*)(ws + off); off += 7 * 8192 * 4;

    // weights transpose (+ zero bcnt)
    wt_kernel<<<14, 256, 0, stream>>>(Wx, W1a, W1b, W1c, W2a, W2b, W2c, Wt, bcnt);

    // h = relu(x @ Wx + bx)  -> bf16
    mlp_mfma<1, 0, true><<<NNP / 128, 256, 0, stream>>>(
        x, nullptr, nullptr, h16, Wt, bx, nullptr, nullptr, nullptr, nullptr);

    // edge partition into fixed bucket regions
    binscatter_kernel<<<NBB, 256, 0, stream>>>(srcp, dstp, ea, bcnt, binned);

    // layer 1: fused bucket-CSR + aggregation, then MLP (in-place on h16)
    bucket_agg_kernel<<<NBUK, 512, 0, stream>>>(bcnt, binned, h16, emb, agg16);
    mlp_mfma<3, 1, true><<<NNP / 128, 256, 0, stream>>>(
        h16, agg16, eps1, h16, Wt + 8192, b1a, Wt + 2 * 8192, b1b, Wt + 3 * 8192, b1c);

    // layer 2 -> d_out fp32
    bucket_agg_kernel<<<NBUK, 512, 0, stream>>>(bcnt, binned, h16, emb, agg16);
    mlp_mfma<3, 1, false><<<NNP / 128, 256, 0, stream>>>(
        h16, agg16, eps2, out, Wt + 4 * 8192, b2a, Wt + 5 * 8192, b2b, Wt + 6 * 8192, b2c);
}